// Round 2
// 1527.738 us; speedup vs baseline: 1.0188x; 1.0188x over previous
//
#include <hip/hip_runtime.h>

#define S_LEN 2048
#define DH 64
#define TK 64
#define NKT (S_LEN / TK)   // 32
#define LDSP 72            // padded LDS row stride in shorts (144 B = 16B-aligned rows)

typedef __attribute__((ext_vector_type(8))) short short8;
typedef __attribute__((ext_vector_type(4))) short short4v;
typedef __attribute__((ext_vector_type(4))) float float4v;
typedef __attribute__((ext_vector_type(4))) int   int4v;

static __device__ __forceinline__ short f2bf(float x) {
    unsigned u = __builtin_bit_cast(unsigned, x);
    u += 0x7fff + ((u >> 16) & 1);   // RNE to bf16
    return (short)(u >> 16);
}

static __device__ __forceinline__ short8 cvt8(float4v a, float4v b) {
    short8 s;
    s[0] = f2bf(a[0]); s[1] = f2bf(a[1]); s[2] = f2bf(a[2]); s[3] = f2bf(a[3]);
    s[4] = f2bf(b[0]); s[5] = f2bf(b[1]); s[6] = f2bf(b[2]); s[7] = f2bf(b[3]);
    return s;
}

// one barrier per tile: drain LDS only (NOT vmcnt — keep prefetch loads and attn
// stores in flight across the barrier). memory clobbers on both sides stop the
// compiler from moving ds ops across the raw s_barrier; sched_barrier(0) pins
// the backend scheduling region at the barrier (rule-18 class hardening).
static __device__ __forceinline__ void tile_barrier() {
    asm volatile("s_waitcnt lgkmcnt(0)" ::: "memory");
    __builtin_amdgcn_s_barrier();
    __builtin_amdgcn_sched_barrier(0);
    asm volatile("" ::: "memory");
}

__global__ __launch_bounds__(256, 2) void attn_kernel(
    const float* __restrict__ q,
    const float* __restrict__ k,
    const float* __restrict__ v,
    const int*   __restrict__ mask,
    float* __restrict__ out,    // [64][2048][64]
    float* __restrict__ attn)   // [64][2048][2048]
{
    __shared__ short Ks[2][TK * LDSP];   // K tiles, permuted row order (double-buffered)
    __shared__ short Vt[2][DH * LDSP];   // transposed V tiles: Vt[d][kk]

    const int tid  = threadIdx.x;
    const int wave = tid >> 6;
    const int lane = tid & 63;
    const int l16  = lane & 15;
    const int quad = lane >> 4;

    const int bid = blockIdx.x;
    const int qt  = bid & 31;    // q-tile fastest: blocks sharing (b,h) share K/V in cache
    const int bh  = bid >> 5;
    const int b   = bh >> 4;     // H = 16
    const int q0  = qt * TK;

    const float* qg = q + ((size_t)bh * S_LEN + q0) * DH;
    const float* kg = k + (size_t)bh * S_LEN * DH;
    const float* vg = v + (size_t)bh * S_LEN * DH;
    const int*   mg = mask + ((size_t)b * S_LEN + q0) * S_LEN;
    float* attng = attn + ((size_t)bh * S_LEN + q0) * (size_t)S_LEN;

    // swapped-operand layout: this lane's q-row (score column) is l16
    const int qrow = wave * 16 + l16;

    // ---- per-thread staging geometry (loop-invariant) ----
    const int krow0 = tid >> 3;            // global k-rows krow0 and krow0+32
    const int kcol8 = (tid & 7) << 3;
    // K-row permutation: LDS row s*16+q*4+r  <->  global kk = 32(s>>1)+8q+4(s&1)+r
    // makes the QK^T output registers directly usable as the PV A-fragment.
    auto permrow = [](int kk) {
        return ((kk & 4) << 2) | (kk & 32) | ((kk & 24) >> 1) | (kk & 3);
    };
    const int kpr0 = permrow(krow0);
    const int kpr1 = permrow(krow0 + 32);
    const int vkb = tid >> 4, vdb = tid & 15;

    // staging registers (issue-early / write-late, T14)
    float4v ks0a, ks0b, ks1a, ks1b;
    float4v vr0, vr1, vr2, vr3;

    auto loadK = [&](int kt) {
        const float* p0 = kg + (size_t)(kt * TK + krow0) * DH + kcol8;
        ks0a = *(const float4v*)(p0);
        ks0b = *(const float4v*)(p0 + 4);
        const float* p1 = p0 + 32 * DH;
        ks1a = *(const float4v*)(p1);
        ks1b = *(const float4v*)(p1 + 4);
    };
    auto writeK = [&](int buf) {
        *(short8*)&Ks[buf][kpr0 * LDSP + kcol8] = cvt8(ks0a, ks0b);
        *(short8*)&Ks[buf][kpr1 * LDSP + kcol8] = cvt8(ks1a, ks1b);
    };
    auto loadV = [&](int kt) {
        const float* vb = vg + (size_t)(kt * TK + vkb * 4) * DH + vdb * 4;
        vr0 = *(const float4v*)(vb);
        vr1 = *(const float4v*)(vb + DH);
        vr2 = *(const float4v*)(vb + 2 * DH);
        vr3 = *(const float4v*)(vb + 3 * DH);
    };
    auto writeV = [&](int buf) {
        #pragma unroll
        for (int t = 0; t < 4; ++t) {
            int i = (t + tid) & 3;   // rotate write order to spread banks
            short4v sv = { f2bf(vr0[i]), f2bf(vr1[i]), f2bf(vr2[i]), f2bf(vr3[i]) };
            *(short4v*)&Vt[buf][(vdb * 4 + i) * LDSP + vkb * 4] = sv;
        }
    };

    // ---- prologue: Q fragments straight into registers (no Qs LDS), stage K0 ----
    const float* qp = qg + (size_t)qrow * DH + quad * 8;
    float4v qa0 = *(const float4v*)(qp);
    float4v qa1 = *(const float4v*)(qp + 4);
    float4v qb0 = *(const float4v*)(qp + 32);
    float4v qb1 = *(const float4v*)(qp + 36);
    loadK(0);
    short8 afr0 = cvt8(qa0, qa1);
    short8 afr1 = cvt8(qb0, qb1);
    writeK(0);

    const int* mrow = mg + (size_t)qrow * S_LEN;
    int4v mk[4], mkn[4];
    #pragma unroll
    for (int s = 0; s < 4; ++s)
        mk[s] = *(const int4v*)(mrow + ((s >> 1) << 5) + (quad << 3) + ((s & 1) << 2));

    tile_barrier();

    // ================= PASS 1: row sums of exp(s) =================
    float rs = 0.f;
    for (int kt = 0; kt < NKT; ++kt) {
        const int cur = kt & 1;
        if (kt + 1 < NKT) {
            loadK(kt + 1);
            #pragma unroll
            for (int s = 0; s < 4; ++s)
                mkn[s] = *(const int4v*)(mrow + (kt + 1) * TK +
                          ((s >> 1) << 5) + (quad << 3) + ((s & 1) << 2));
        } else {
            loadK(0);   // pass-2 tile 0 prefetch under the last pass-1 tile
            loadV(0);
        }
        #pragma unroll
        for (int s = 0; s < 4; ++s) {
            float4v acc = {0.f, 0.f, 0.f, 0.f};
            const short* kr = &Ks[cur][(s * 16 + l16) * LDSP + quad * 8];
            short8 b0 = *(const short8*)(kr);
            short8 b1 = *(const short8*)(kr + 32);
            acc = __builtin_amdgcn_mfma_f32_16x16x32_bf16(b0, afr0, acc, 0, 0, 0);
            acc = __builtin_amdgcn_mfma_f32_16x16x32_bf16(b1, afr1, acc, 0, 0, 0);
            #pragma unroll
            for (int r = 0; r < 4; ++r)
                rs += mk[s][r] ? __expf(acc[r] * 0.125f) : 0.f;
        }
        if (kt + 1 < NKT) {
            writeK(cur ^ 1);
            #pragma unroll
            for (int s = 0; s < 4; ++s) mk[s] = mkn[s];
        } else {
            writeK(cur ^ 1);   // kt=31: cur^1 == 0 -> pass-2 tile 0
            writeV(cur ^ 1);
        }
        tile_barrier();
    }

    // reduce row sum across the 4 quads sharing this q-row; keep reciprocal
    // (reload mask tile 0 first so the loads overlap the shuffles)
    #pragma unroll
    for (int s = 0; s < 4; ++s)
        mk[s] = *(const int4v*)(mrow + ((s >> 1) << 5) + (quad << 3) + ((s & 1) << 2));
    rs += __shfl_xor(rs, 16);
    rs += __shfl_xor(rs, 32);
    rs = 1.0f / rs;

    // ================= PASS 2: write attn + PV =================
    float4v oacc[4];
    #pragma unroll
    for (int i = 0; i < 4; ++i) oacc[i] = (float4v){0.f, 0.f, 0.f, 0.f};
    float* arow = attng + (size_t)qrow * S_LEN;

    for (int kt = 0; kt < NKT; ++kt) {
        const int cur = kt & 1;
        if (kt + 1 < NKT) {
            loadK(kt + 1);
            loadV(kt + 1);
            #pragma unroll
            for (int s = 0; s < 4; ++s)
                mkn[s] = *(const int4v*)(mrow + (kt + 1) * TK +
                          ((s >> 1) << 5) + (quad << 3) + ((s & 1) << 2));
        }
        float p[4][4];
        #pragma unroll
        for (int s = 0; s < 4; ++s) {
            float4v acc = {0.f, 0.f, 0.f, 0.f};
            const short* kr = &Ks[cur][(s * 16 + l16) * LDSP + quad * 8];
            short8 b0 = *(const short8*)(kr);
            short8 b1 = *(const short8*)(kr + 32);
            acc = __builtin_amdgcn_mfma_f32_16x16x32_bf16(b0, afr0, acc, 0, 0, 0);
            acc = __builtin_amdgcn_mfma_f32_16x16x32_bf16(b1, afr1, acc, 0, 0, 0);
            float4v pv;
            #pragma unroll
            for (int r = 0; r < 4; ++r) {
                float pe = mk[s][r] ? __expf(acc[r] * 0.125f) * rs : 0.f;
                p[s][r] = pe;
                pv[r] = pe;
            }
            // 4 consecutive k per lane -> one nontemporal dwordx4 (attn is write-once)
            __builtin_nontemporal_store(pv,
                (float4v*)(arow + kt * TK + ((s >> 1) << 5) + (quad << 3) + ((s & 1) << 2)));
        }
        // PV: score registers ARE the A-fragment (thanks to the K-row permutation)
        #pragma unroll
        for (int ks = 0; ks < 2; ++ks) {
            short8 pa;
            pa[0] = f2bf(p[2 * ks][0]);     pa[1] = f2bf(p[2 * ks][1]);
            pa[2] = f2bf(p[2 * ks][2]);     pa[3] = f2bf(p[2 * ks][3]);
            pa[4] = f2bf(p[2 * ks + 1][0]); pa[5] = f2bf(p[2 * ks + 1][1]);
            pa[6] = f2bf(p[2 * ks + 1][2]); pa[7] = f2bf(p[2 * ks + 1][3]);
            #pragma unroll
            for (int dsub = 0; dsub < 4; ++dsub) {
                short8 bv = *(const short8*)&Vt[cur][(dsub * 16 + l16) * LDSP + ks * 32 + quad * 8];
                oacc[dsub] = __builtin_amdgcn_mfma_f32_16x16x32_bf16(pa, bv, oacc[dsub], 0, 0, 0);
            }
        }
        if (kt + 1 < NKT) {
            writeK(cur ^ 1);
            writeV(cur ^ 1);
            #pragma unroll
            for (int s = 0; s < 4; ++s) mk[s] = mkn[s];
        }
        tile_barrier();
    }

    // ---- epilogue: store output tile ----
    float* og = out + ((size_t)bh * S_LEN + q0) * DH;
    #pragma unroll
    for (int dsub = 0; dsub < 4; ++dsub) {
        #pragma unroll
        for (int r = 0; r < 4; ++r) {
            og[(size_t)(wave * 16 + quad * 4 + r) * DH + dsub * 16 + l16] = oacc[dsub][r];
        }
    }
}

extern "C" void kernel_launch(void* const* d_in, const int* in_sizes, int n_in,
                              void* d_out, int out_size, void* d_ws, size_t ws_size,
                              hipStream_t stream) {
    (void)in_sizes; (void)n_in; (void)out_size; (void)d_ws; (void)ws_size;
    const float* q    = (const float*)d_in[0];
    const float* k    = (const float*)d_in[1];
    const float* v    = (const float*)d_in[2];
    const int*   mask = (const int*)d_in[3];
    float* out  = (float*)d_out;
    float* attn = out + (size_t)4 * 16 * 2048 * 64;   // outputs concatenated: (output, attn)
    attn_kernel<<<dim3(2048), dim3(256), 0, stream>>>(q, k, v, mask, out, attn);
}